// Round 7
// baseline (2943.889 us; speedup 1.0000x reference)
//
#include <hip/hip_runtime.h>

#define NN 1024
#define DD 128

typedef __attribute__((ext_vector_type(4))) float f32x4;

union PSh {
    float hS[2][DD];                                    // embuv
    struct { float red[4][64][17]; } agg;               // agg (pad 17 -> conflict-free)
    struct { float aggS[2][DD], uS[2][DD], gpart[2][2][DD], hS2[2][DD]; float sred[2][2]; } g;
};

// monotonic-counter grid barrier; all 1024 blocks co-resident (4 blocks/CU guaranteed
// by LDS 17.4KB and __launch_bounds__(256,4)). Byte-identical semantics to round 4 (proven).
__device__ __forceinline__ void gridbar(unsigned* bar, unsigned target, int tid) {
    __syncthreads();
    if (tid == 0) {
        __threadfence();
        __hip_atomic_fetch_add(bar, 1u, __ATOMIC_RELEASE, __HIP_MEMORY_SCOPE_AGENT);
        while (__hip_atomic_load(bar, __ATOMIC_ACQUIRE, __HIP_MEMORY_SCOPE_AGENT) < target)
            __builtin_amdgcn_s_sleep(1);
        __threadfence();
    }
    __syncthreads();
}

__global__ __launch_bounds__(256, 4) void k_persist(
    const float* __restrict__ nf, const float* __restrict__ adj,
    const float* __restrict__ We, const float* __restrict__ be,
    const float* __restrict__ Wu_all, const float* __restrict__ bu_all,
    const float* __restrict__ Wv_all, const float* __restrict__ bv_all,
    const float* __restrict__ Wg_all, const float* __restrict__ bg_all,
    const float* __restrict__ Wc1, const float* __restrict__ bc1, const float* __restrict__ Wc2,
    float* __restrict__ h, float* __restrict__ u,
    float* __restrict__ v0, float* __restrict__ v1, float* __restrict__ P,
    float* __restrict__ hi, float* __restrict__ hj,
    float* __restrict__ S1, float* __restrict__ S2,
    unsigned* __restrict__ ctrl)
{
    __shared__ PSh sh;
    const int b = blockIdx.x, tid = threadIdx.x;
    const int d = tid & 127, half = tid >> 7;
    unsigned* bar = ctrl;
    unsigned tgt = 1024;

    // ---------------- P0: embed + u0/v0 GEMMs (blocks 0..511, 2 rows each) ----------------
    if (b < 512) {
        int m0 = b * 2;
        if (half == 0) {
#pragma unroll
            for (int r = 0; r < 2; ++r) {
                float a = be[d];
#pragma unroll
                for (int k = 0; k < 3; ++k) a = fmaf(nf[(m0 + r) * 3 + k], We[k * DD + d], a);
                h[(m0 + r) * DD + d] = a;
                sh.hS[r][d] = a;
            }
        }
        __syncthreads();
        const float* W = half ? Wv_all : Wu_all;
        float a0 = 0.f, a1 = 0.f;
#pragma unroll 4
        for (int k4 = 0; k4 < DD; k4 += 4) {
            f32x4 h0 = *(const f32x4*)&sh.hS[0][k4];
            f32x4 h1 = *(const f32x4*)&sh.hS[1][k4];
#pragma unroll
            for (int kk = 0; kk < 4; ++kk) {
                float w = W[(k4 + kk) * DD + d];
                a0 = fmaf(h0[kk], w, a0);
                a1 = fmaf(h1[kk], w, a1);
            }
        }
        float bb = half ? bv_all[d] : bu_all[d];
        float* out = half ? v0 : u;
        out[m0 * DD + d] = a0 + bb;
        out[(m0 + 1) * DD + d] = a1 + bb;
    }
    gridbar(bar, tgt, tid); tgt += 1024;

    for (int l = 0; l < 3; ++l) {
        const float* vcur = (l == 1) ? v1 : v0;
        // ---------------- agg partials: 128 rowgroups(8) x 8 kchunks ----------------
        {
            int rg = b >> 3, kc = b & 7;
            int m0 = rg * 8;
            int w = tid >> 6, lane = tid & 63;
            int kbase = kc * 128 + w * 32;
            int c2 = lane * 2;
            float acc[8][2] = {};
            const float* vp = vcur + (size_t)kbase * DD + c2;
#pragma unroll
            for (int kk4 = 0; kk4 < 32; kk4 += 4) {
                f32x4 a[8];
#pragma unroll
                for (int r = 0; r < 8; ++r)
                    a[r] = *(const f32x4*)(adj + (size_t)(m0 + r) * NN + kbase + kk4); // uniform -> s_load
#pragma unroll
                for (int kk = 0; kk < 4; ++kk) {
                    float2 v2 = *(const float2*)(vp + (kk4 + kk) * DD);
#pragma unroll
                    for (int r = 0; r < 8; ++r) {
                        acc[r][0] = fmaf(a[r][kk], v2.x, acc[r][0]);
                        acc[r][1] = fmaf(a[r][kk], v2.y, acc[r][1]);
                    }
                }
            }
#pragma unroll
            for (int r = 0; r < 8; ++r) {
                sh.agg.red[w][lane][r * 2] = acc[r][0];
                sh.agg.red[w][lane][r * 2 + 1] = acc[r][1];
            }
            __syncthreads();
            float* Pk = P + (size_t)kc * (NN * DD);
#pragma unroll
            for (int rr = 0; rr < 2; ++rr) {
                int r = w * 2 + rr;
                float s0 = 0.f, s1 = 0.f;
#pragma unroll
                for (int ww = 0; ww < 4; ++ww) {
                    s0 += sh.agg.red[ww][lane][r * 2];
                    s1 += sh.agg.red[ww][lane][r * 2 + 1];
                }
                *(float2*)(Pk + (size_t)(m0 + r) * DD + c2) = make_float2(s0, s1);
            }
        }
        gridbar(bar, tgt, tid); tgt += 1024;

        // ---------------- gate + h update + (next u/v | classifier) : blocks 0..511 ----------------
        if (b < 512) {
            int m0 = b * 2;
            if (l == 2 && tid < 4) sh.g.sred[tid >> 1][tid & 1] = 0.f;
            {
                int idx = (m0 + half) * DD + d;
                float s = 0.f;
#pragma unroll
                for (int c = 0; c < 8; ++c) s += P[(size_t)c * (NN * DD) + idx];
                sh.g.aggS[half][d] = s;
                sh.g.uS[half][d] = u[idx];
            }
            __syncthreads();
            {   // gate partial: half0 = u@WA, half1 = agg@WB
                const float* W = Wg_all + l * (2 * DD * DD) + (half ? DD * DD : 0);
                const float(*X)[DD] = half ? sh.g.aggS : sh.g.uS;
                float g0 = 0.f, g1 = 0.f;
#pragma unroll 4
                for (int k4 = 0; k4 < DD; k4 += 4) {
                    f32x4 x0 = *(const f32x4*)&X[0][k4];
                    f32x4 x1 = *(const f32x4*)&X[1][k4];
#pragma unroll
                    for (int kk = 0; kk < 4; ++kk) {
                        float w = W[(k4 + kk) * DD + d];
                        g0 = fmaf(x0[kk], w, g0);
                        g1 = fmaf(x1[kk], w, g1);
                    }
                }
                sh.g.gpart[half][0][d] = g0;
                sh.g.gpart[half][1][d] = g1;
            }
            __syncthreads();
            {
                float z = sh.g.gpart[0][half][d] + sh.g.gpart[1][half][d] + bg_all[l * DD + d];
                float g = 1.f / (1.f + __expf(-z));
                float nh = fmaf(g, sh.g.aggS[half][d], h[(m0 + half) * DD + d]);
                nh = nh > 0.f ? nh : 0.f;
                h[(m0 + half) * DD + d] = nh;
                sh.g.hS2[half][d] = nh;
            }
            __syncthreads();
            if (l < 2) {
                const float* W2 = half ? (Wv_all + (l + 1) * DD * DD) : (Wu_all + (l + 1) * DD * DD);
                float a0 = 0.f, a1 = 0.f;
#pragma unroll 4
                for (int k4 = 0; k4 < DD; k4 += 4) {
                    f32x4 h0 = *(const f32x4*)&sh.g.hS2[0][k4];
                    f32x4 h1 = *(const f32x4*)&sh.g.hS2[1][k4];
#pragma unroll
                    for (int kk = 0; kk < 4; ++kk) {
                        float w = W2[(k4 + kk) * DD + d];
                        a0 = fmaf(h0[kk], w, a0);
                        a1 = fmaf(h1[kk], w, a1);
                    }
                }
                float bb = half ? bv_all[(l + 1) * DD + d] : bu_all[(l + 1) * DD + d];
                float* out = half ? ((l == 0) ? v1 : v0) : u;
                out[m0 * DD + d] = a0 + bb;
                out[(m0 + 1) * DD + d] = a1 + bb;
            } else {
                const float* W2 = Wc1 + (half ? DD * DD : 0);
                float a0 = 0.f, a1 = 0.f;
#pragma unroll 4
                for (int k4 = 0; k4 < DD; k4 += 4) {
                    f32x4 h0 = *(const f32x4*)&sh.g.hS2[0][k4];
                    f32x4 h1 = *(const f32x4*)&sh.g.hS2[1][k4];
#pragma unroll
                    for (int kk = 0; kk < 4; ++kk) {
                        float w = W2[(k4 + kk) * DD + d];
                        a0 = fmaf(h0[kk], w, a0);
                        a1 = fmaf(h1[kk], w, a1);
                    }
                }
                float wv = Wc2[d];
                float bcv = half ? 0.f : bc1[d];
                float* out = half ? hj : hi;
#pragma unroll
                for (int r = 0; r < 2; ++r) {
                    float val = (r ? a1 : a0) + bcv;
                    out[(m0 + r) * DD + d] = val;
                    float p = val * wv;
#pragma unroll
                    for (int off = 32; off; off >>= 1) p += __shfl_down(p, off);
                    if ((tid & 63) == 0) atomicAdd(&sh.g.sred[half][r], p);
                }
                __syncthreads();
                if (tid < 2) S1[m0 + tid] = sh.g.sred[0][tid];
                else if (tid < 4) S2[m0 + tid - 2] = sh.g.sred[1][tid - 2];
            }
        }
        if (l < 2) { gridbar(bar, tgt, tid); tgt += 1024; }
    }
}

// ---------------- k_edge: logits + loss; 64x64 tiles, 4x4 micro; relu via |x| ----------------
__global__ __launch_bounds__(256) void k_edge(
    const float* __restrict__ hi, const float* __restrict__ hj,
    const float* __restrict__ S1, const float* __restrict__ S2,
    const float* __restrict__ Wc2, const float* __restrict__ bc2,
    const float* __restrict__ adj, const float* __restrict__ ew,
    float* __restrict__ outL, unsigned* __restrict__ ctrl)
{
    __shared__ float hiT[128][68];   // stride 68 keeps float4 rows 16B-aligned
    __shared__ float hjT[128][68];
    __shared__ float lred;
    int tid = threadIdx.x;
    int i0 = (blockIdx.x >> 4) * 64, j0 = (blockIdx.x & 15) * 64;
    if (tid == 0) lred = 0.f;
    for (int e = tid; e < 64 * 128; e += 256) {
        int r = e >> 7, hh = e & 127;
        hiT[hh][r] = hi[(i0 + r) * DD + hh];
        hjT[hh][r] = hj[(j0 + r) * DD + hh];
    }
    __syncthreads();
    int tx = tid & 15, ty = tid >> 4;
    float acc[4][4] = {};
#pragma unroll 4
    for (int hh = 0; hh < 128; ++hh) {
        f32x4 a = *(const f32x4*)&hiT[hh][ty * 4];
        f32x4 bb = *(const f32x4*)&hjT[hh][tx * 4];
        float w = Wc2[hh];                        // wave-uniform -> s_load
#pragma unroll
        for (int p = 0; p < 4; ++p)
#pragma unroll
            for (int q = 0; q < 4; ++q) {
                float x = a[p] + bb[q];
                acc[p][q] = fmaf(fabsf(x), w, acc[p][q]);
            }
    }
    float bcv = bc2[0];
    float ls = 0.f;
#pragma unroll
    for (int p = 0; p < 4; ++p) {
        int i = i0 + ty * 4 + p;
        float s1 = S1[i];
        int jb = j0 + tx * 4;
        f32x4 s2 = *(const f32x4*)(S2 + jb);
        f32x4 lg;
#pragma unroll
        for (int q = 0; q < 4; ++q)
            lg[q] = fmaf(0.5f, acc[p][q] + s1 + s2[q], bcv);
        *(f32x4*)(outL + (size_t)i * NN + jb) = lg;
        f32x4 a4 = *(const f32x4*)(adj + (size_t)i * NN + jb);
        f32x4 e4 = *(const f32x4*)(ew + (size_t)i * NN + jb);
#pragma unroll
        for (int q = 0; q < 4; ++q) {
            float t = fmaf(lg[q], a4[q], -e4[q]);
            ls = fmaf(t, t, ls);
        }
    }
#pragma unroll
    for (int off = 32; off; off >>= 1) ls += __shfl_down(ls, off);
    if ((tid & 63) == 0) atomicAdd(&lred, ls);
    __syncthreads();
    if (tid == 0) {
        float* lossAcc = (float*)(ctrl + 2);
        atomicAdd(lossAcc, lred);
        __threadfence();
        unsigned old = atomicAdd(ctrl + 1, 1u);
        if (old == 255u) {
            __threadfence();
            outL[(size_t)NN * NN] = (*(volatile float*)lossAcc) * (1.f / (1024.f * 1024.f));
        }
    }
}

extern "C" void kernel_launch(void* const* d_in, const int* in_sizes, int n_in,
                              void* d_out, int out_size, void* d_ws, size_t ws_size,
                              hipStream_t stream)
{
    const float* nf  = (const float*)d_in[0];
    const float* adj = (const float*)d_in[1];
    const float* ew  = (const float*)d_in[2];
    const float* We  = (const float*)d_in[3];
    const float* be  = (const float*)d_in[4];
    const float* Wu  = (const float*)d_in[5];
    const float* bu  = (const float*)d_in[6];
    const float* Wv  = (const float*)d_in[7];
    const float* bv  = (const float*)d_in[8];
    const float* Wg  = (const float*)d_in[9];
    const float* bg  = (const float*)d_in[10];
    const float* Wc1 = (const float*)d_in[11];
    const float* bc1 = (const float*)d_in[12];
    const float* Wc2 = (const float*)d_in[13];
    const float* bc2 = (const float*)d_in[14];

    float* ws = (float*)d_ws;
    float* h   = ws;                       // 131072
    float* u   = ws + 131072;              // 131072
    float* v0  = ws + 262144;              // 131072
    float* v1  = ws + 393216;              // 131072
    float* hi  = ws + 524288;              // 131072
    float* hj  = ws + 655360;              // 131072
    float* P   = ws + 786432;              // 8 x 131072
    float* S1  = ws + 1835008;             // 1024
    float* S2  = ws + 1836032;             // 1024
    unsigned* ctrl = (unsigned*)(ws + 1837056);   // [bar, edgeCnt, lossAcc, pad]

    hipMemsetAsync(ctrl, 0, 16, stream);   // barrier/counters must be zero BEFORE launch
    k_persist<<<1024, 256, 0, stream>>>(nf, adj, We, be, Wu, bu, Wv, bv, Wg, bg,
                                        Wc1, bc1, Wc2, h, u, v0, v1, P,
                                        hi, hj, S1, S2, ctrl);
    k_edge<<<256, 256, 0, stream>>>(hi, hj, S1, S2, Wc2, bc2, adj, ew,
                                    (float*)d_out, ctrl);
}

// Round 8
// 2642.820 us; speedup vs baseline: 1.1139x; 1.1139x over previous
//
#include <hip/hip_runtime.h>

#define NN 1024
#define DD 128

typedef __attribute__((ext_vector_type(4))) float f32x4;

union PSh {
    float hS[2][DD];                                    // embuv
    struct { float red[4][64][17]; } agg;               // agg (pad 17 -> conflict-free)
    struct { float aggS[2][DD], uS[2][DD], gpart[2][2][DD], hS2[2][DD]; float sred[2][2]; } g;
};

// ctrl layout (unsigned words):
//  [g*32] g=0..31 : group counters (128 B apart)
//  [1024]         : master counter
//  [1056]         : release flag (single writer per phase)
//  [1088]         : edge completion counter
//  [1089]         : lossAcc (float)
#define CTRL_WORDS 1152

// Two-level tree barrier + broadcast flag. 1024 blocks = 32 groups x 32.
// Adds spread over 32 cachelines; spinners poll the single-writer release
// flag every ~512 cyc -> ~MB/s of poll traffic instead of GB/s.
__device__ __forceinline__ void gridbar(unsigned* ctrl, unsigned phase, int b, int tid) {
    __syncthreads();
    if (tid == 0) {
        unsigned* gctr    = ctrl + ((b >> 5) << 5);
        unsigned* master  = ctrl + 1024;
        unsigned* release = ctrl + 1056;
        __threadfence();   // make this block's global stores visible device-wide
        unsigned o = __hip_atomic_fetch_add(gctr, 1u, __ATOMIC_RELEASE, __HIP_MEMORY_SCOPE_AGENT);
        if ((o & 31u) == 31u) {
            unsigned m = __hip_atomic_fetch_add(master, 1u, __ATOMIC_ACQ_REL, __HIP_MEMORY_SCOPE_AGENT);
            if ((m & 31u) == 31u)
                __hip_atomic_store(release, phase, __ATOMIC_RELEASE, __HIP_MEMORY_SCOPE_AGENT);
        }
        while (__hip_atomic_load(release, __ATOMIC_ACQUIRE, __HIP_MEMORY_SCOPE_AGENT) < phase)
            __builtin_amdgcn_s_sleep(8);
        __threadfence();   // acquire side: invalidate L1 before reading others' data
    }
    __syncthreads();
}

__global__ __launch_bounds__(256, 4) void k_persist(
    const float* __restrict__ nf, const float* __restrict__ adj,
    const float* __restrict__ We, const float* __restrict__ be,
    const float* __restrict__ Wu_all, const float* __restrict__ bu_all,
    const float* __restrict__ Wv_all, const float* __restrict__ bv_all,
    const float* __restrict__ Wg_all, const float* __restrict__ bg_all,
    const float* __restrict__ Wc1, const float* __restrict__ bc1, const float* __restrict__ Wc2,
    float* __restrict__ h, float* __restrict__ u,
    float* __restrict__ v0, float* __restrict__ v1, float* __restrict__ P,
    float* __restrict__ hi, float* __restrict__ hj,
    float* __restrict__ S1, float* __restrict__ S2,
    unsigned* __restrict__ ctrl)
{
    __shared__ PSh sh;
    const int b = blockIdx.x, tid = threadIdx.x;
    const int d = tid & 127, half = tid >> 7;
    unsigned phase = 1;

    // ---------------- P0: embed + u0/v0 GEMMs (blocks 0..511, 2 rows each) ----------------
    if (b < 512) {
        int m0 = b * 2;
        if (half == 0) {
#pragma unroll
            for (int r = 0; r < 2; ++r) {
                float a = be[d];
#pragma unroll
                for (int k = 0; k < 3; ++k) a = fmaf(nf[(m0 + r) * 3 + k], We[k * DD + d], a);
                h[(m0 + r) * DD + d] = a;
                sh.hS[r][d] = a;
            }
        }
        __syncthreads();
        const float* W = half ? Wv_all : Wu_all;
        float a0 = 0.f, a1 = 0.f;
#pragma unroll 4
        for (int k4 = 0; k4 < DD; k4 += 4) {
            f32x4 h0 = *(const f32x4*)&sh.hS[0][k4];
            f32x4 h1 = *(const f32x4*)&sh.hS[1][k4];
#pragma unroll
            for (int kk = 0; kk < 4; ++kk) {
                float w = W[(k4 + kk) * DD + d];
                a0 = fmaf(h0[kk], w, a0);
                a1 = fmaf(h1[kk], w, a1);
            }
        }
        float bb = half ? bv_all[d] : bu_all[d];
        float* out = half ? v0 : u;
        out[m0 * DD + d] = a0 + bb;
        out[(m0 + 1) * DD + d] = a1 + bb;
    }
    gridbar(ctrl, phase, b, tid); ++phase;

    for (int l = 0; l < 3; ++l) {
        const float* vcur = (l == 1) ? v1 : v0;
        // ---------------- agg partials: 128 rowgroups(8) x 8 kchunks, all 1024 blocks ----------------
        {
            int rg = b >> 3, kc = b & 7;
            int m0 = rg * 8;
            int w = tid >> 6, lane = tid & 63;
            int kbase = kc * 128 + w * 32;
            int c2 = lane * 2;
            float acc[8][2] = {};
            const float* vp = vcur + (size_t)kbase * DD + c2;
#pragma unroll
            for (int kk4 = 0; kk4 < 32; kk4 += 4) {
                f32x4 a[8];
#pragma unroll
                for (int r = 0; r < 8; ++r)
                    a[r] = *(const f32x4*)(adj + (size_t)(m0 + r) * NN + kbase + kk4); // uniform -> s_load
#pragma unroll
                for (int kk = 0; kk < 4; ++kk) {
                    float2 v2 = *(const float2*)(vp + (kk4 + kk) * DD);
#pragma unroll
                    for (int r = 0; r < 8; ++r) {
                        acc[r][0] = fmaf(a[r][kk], v2.x, acc[r][0]);
                        acc[r][1] = fmaf(a[r][kk], v2.y, acc[r][1]);
                    }
                }
            }
#pragma unroll
            for (int r = 0; r < 8; ++r) {
                sh.agg.red[w][lane][r * 2] = acc[r][0];
                sh.agg.red[w][lane][r * 2 + 1] = acc[r][1];
            }
            __syncthreads();
            float* Pk = P + (size_t)kc * (NN * DD);
#pragma unroll
            for (int rr = 0; rr < 2; ++rr) {
                int r = w * 2 + rr;
                float s0 = 0.f, s1 = 0.f;
#pragma unroll
                for (int ww = 0; ww < 4; ++ww) {
                    s0 += sh.agg.red[ww][lane][r * 2];
                    s1 += sh.agg.red[ww][lane][r * 2 + 1];
                }
                *(float2*)(Pk + (size_t)(m0 + r) * DD + c2) = make_float2(s0, s1);
            }
        }
        gridbar(ctrl, phase, b, tid); ++phase;

        // ---------------- gate + h update + (next u/v | classifier): blocks 0..511 ----------------
        if (b < 512) {
            int m0 = b * 2;
            if (l == 2 && tid < 4) sh.g.sred[tid >> 1][tid & 1] = 0.f;
            {
                int idx = (m0 + half) * DD + d;
                float s = 0.f;
#pragma unroll
                for (int c = 0; c < 8; ++c) s += P[(size_t)c * (NN * DD) + idx];
                sh.g.aggS[half][d] = s;
                sh.g.uS[half][d] = u[idx];
            }
            __syncthreads();
            {   // gate partial: half0 = u@WA, half1 = agg@WB
                const float* W = Wg_all + l * (2 * DD * DD) + (half ? DD * DD : 0);
                const float(*X)[DD] = half ? sh.g.aggS : sh.g.uS;
                float g0 = 0.f, g1 = 0.f;
#pragma unroll 4
                for (int k4 = 0; k4 < DD; k4 += 4) {
                    f32x4 x0 = *(const f32x4*)&X[0][k4];
                    f32x4 x1 = *(const f32x4*)&X[1][k4];
#pragma unroll
                    for (int kk = 0; kk < 4; ++kk) {
                        float w = W[(k4 + kk) * DD + d];
                        g0 = fmaf(x0[kk], w, g0);
                        g1 = fmaf(x1[kk], w, g1);
                    }
                }
                sh.g.gpart[half][0][d] = g0;
                sh.g.gpart[half][1][d] = g1;
            }
            __syncthreads();
            {
                float z = sh.g.gpart[0][half][d] + sh.g.gpart[1][half][d] + bg_all[l * DD + d];
                float g = 1.f / (1.f + __expf(-z));
                float nh = fmaf(g, sh.g.aggS[half][d], h[(m0 + half) * DD + d]);
                nh = nh > 0.f ? nh : 0.f;
                h[(m0 + half) * DD + d] = nh;
                sh.g.hS2[half][d] = nh;
            }
            __syncthreads();
            if (l < 2) {
                const float* W2 = half ? (Wv_all + (l + 1) * DD * DD) : (Wu_all + (l + 1) * DD * DD);
                float a0 = 0.f, a1 = 0.f;
#pragma unroll 4
                for (int k4 = 0; k4 < DD; k4 += 4) {
                    f32x4 h0 = *(const f32x4*)&sh.g.hS2[0][k4];
                    f32x4 h1 = *(const f32x4*)&sh.g.hS2[1][k4];
#pragma unroll
                    for (int kk = 0; kk < 4; ++kk) {
                        float w = W2[(k4 + kk) * DD + d];
                        a0 = fmaf(h0[kk], w, a0);
                        a1 = fmaf(h1[kk], w, a1);
                    }
                }
                float bb = half ? bv_all[(l + 1) * DD + d] : bu_all[(l + 1) * DD + d];
                float* out = half ? ((l == 0) ? v1 : v0) : u;
                out[m0 * DD + d] = a0 + bb;
                out[(m0 + 1) * DD + d] = a1 + bb;
            } else {
                const float* W2 = Wc1 + (half ? DD * DD : 0);
                float a0 = 0.f, a1 = 0.f;
#pragma unroll 4
                for (int k4 = 0; k4 < DD; k4 += 4) {
                    f32x4 h0 = *(const f32x4*)&sh.g.hS2[0][k4];
                    f32x4 h1 = *(const f32x4*)&sh.g.hS2[1][k4];
#pragma unroll
                    for (int kk = 0; kk < 4; ++kk) {
                        float w = W2[(k4 + kk) * DD + d];
                        a0 = fmaf(h0[kk], w, a0);
                        a1 = fmaf(h1[kk], w, a1);
                    }
                }
                float wv = Wc2[d];
                float bcv = half ? 0.f : bc1[d];
                float* out = half ? hj : hi;
#pragma unroll
                for (int r = 0; r < 2; ++r) {
                    float val = (r ? a1 : a0) + bcv;
                    out[(m0 + r) * DD + d] = val;
                    float p = val * wv;
#pragma unroll
                    for (int off = 32; off; off >>= 1) p += __shfl_down(p, off);
                    if ((tid & 63) == 0) atomicAdd(&sh.g.sred[half][r], p);
                }
                __syncthreads();
                if (tid < 2) S1[m0 + tid] = sh.g.sred[0][tid];
                else if (tid < 4) S2[m0 + tid - 2] = sh.g.sred[1][tid - 2];
            }
        }
        if (l < 2) { gridbar(ctrl, phase, b, tid); ++phase; }
    }
}

// ---------------- k_edge: logits + loss; 64x64 tiles, 4x4 micro; relu via |x| ----------------
__global__ __launch_bounds__(256) void k_edge(
    const float* __restrict__ hi, const float* __restrict__ hj,
    const float* __restrict__ S1, const float* __restrict__ S2,
    const float* __restrict__ Wc2, const float* __restrict__ bc2,
    const float* __restrict__ adj, const float* __restrict__ ew,
    float* __restrict__ outL, unsigned* __restrict__ ctrl)
{
    __shared__ float hiT[128][68];   // stride 68 keeps float4 rows 16B-aligned
    __shared__ float hjT[128][68];
    __shared__ float lred;
    int tid = threadIdx.x;
    int i0 = (blockIdx.x >> 4) * 64, j0 = (blockIdx.x & 15) * 64;
    if (tid == 0) lred = 0.f;
    for (int e = tid; e < 64 * 128; e += 256) {
        int r = e >> 7, hh = e & 127;
        hiT[hh][r] = hi[(i0 + r) * DD + hh];
        hjT[hh][r] = hj[(j0 + r) * DD + hh];
    }
    __syncthreads();
    int tx = tid & 15, ty = tid >> 4;
    float acc[4][4] = {};
#pragma unroll 4
    for (int hh = 0; hh < 128; ++hh) {
        f32x4 a = *(const f32x4*)&hiT[hh][ty * 4];
        f32x4 bb = *(const f32x4*)&hjT[hh][tx * 4];
        float w = Wc2[hh];                        // wave-uniform -> s_load
#pragma unroll
        for (int p = 0; p < 4; ++p)
#pragma unroll
            for (int q = 0; q < 4; ++q) {
                float x = a[p] + bb[q];
                acc[p][q] = fmaf(fabsf(x), w, acc[p][q]);
            }
    }
    float bcv = bc2[0];
    float ls = 0.f;
#pragma unroll
    for (int p = 0; p < 4; ++p) {
        int i = i0 + ty * 4 + p;
        float s1 = S1[i];
        int jb = j0 + tx * 4;
        f32x4 s2 = *(const f32x4*)(S2 + jb);
        f32x4 lg;
#pragma unroll
        for (int q = 0; q < 4; ++q)
            lg[q] = fmaf(0.5f, acc[p][q] + s1 + s2[q], bcv);
        *(f32x4*)(outL + (size_t)i * NN + jb) = lg;
        f32x4 a4 = *(const f32x4*)(adj + (size_t)i * NN + jb);
        f32x4 e4 = *(const f32x4*)(ew + (size_t)i * NN + jb);
#pragma unroll
        for (int q = 0; q < 4; ++q) {
            float t = fmaf(lg[q], a4[q], -e4[q]);
            ls = fmaf(t, t, ls);
        }
    }
#pragma unroll
    for (int off = 32; off; off >>= 1) ls += __shfl_down(ls, off);
    if ((tid & 63) == 0) atomicAdd(&lred, ls);
    __syncthreads();
    if (tid == 0) {
        float* lossAcc = (float*)(ctrl + 1089);
        atomicAdd(lossAcc, lred);
        __threadfence();
        unsigned old = atomicAdd(ctrl + 1088, 1u);
        if (old == 255u) {
            __threadfence();
            outL[(size_t)NN * NN] = (*(volatile float*)lossAcc) * (1.f / (1024.f * 1024.f));
        }
    }
}

extern "C" void kernel_launch(void* const* d_in, const int* in_sizes, int n_in,
                              void* d_out, int out_size, void* d_ws, size_t ws_size,
                              hipStream_t stream)
{
    const float* nf  = (const float*)d_in[0];
    const float* adj = (const float*)d_in[1];
    const float* ew  = (const float*)d_in[2];
    const float* We  = (const float*)d_in[3];
    const float* be  = (const float*)d_in[4];
    const float* Wu  = (const float*)d_in[5];
    const float* bu  = (const float*)d_in[6];
    const float* Wv  = (const float*)d_in[7];
    const float* bv  = (const float*)d_in[8];
    const float* Wg  = (const float*)d_in[9];
    const float* bg  = (const float*)d_in[10];
    const float* Wc1 = (const float*)d_in[11];
    const float* bc1 = (const float*)d_in[12];
    const float* Wc2 = (const float*)d_in[13];
    const float* bc2 = (const float*)d_in[14];

    float* ws = (float*)d_ws;
    float* h   = ws;                       // 131072
    float* u   = ws + 131072;              // 131072
    float* v0  = ws + 262144;              // 131072
    float* v1  = ws + 393216;              // 131072
    float* hi  = ws + 524288;              // 131072
    float* hj  = ws + 655360;              // 131072
    float* P   = ws + 786432;              // 8 x 131072
    float* S1  = ws + 1835008;             // 1024
    float* S2  = ws + 1836032;             // 1024
    unsigned* ctrl = (unsigned*)(ws + 1837056);   // CTRL_WORDS

    hipMemsetAsync(ctrl, 0, CTRL_WORDS * 4, stream);   // counters zero BEFORE launch
    k_persist<<<1024, 256, 0, stream>>>(nf, adj, We, be, Wu, bu, Wv, bv, Wg, bg,
                                        Wc1, bc1, Wc2, h, u, v0, v1, P,
                                        hi, hj, S1, S2, ctrl);
    k_edge<<<256, 256, 0, stream>>>(hi, hj, S1, S2, Wc2, bc2, adj, ew,
                                    (float*)d_out, ctrl);
}